// Round 1
// baseline (704.988 us; speedup 1.0000x reference)
//
#include <hip/hip_runtime.h>
#include <math.h>

namespace {
constexpr int B    = 8;
constexpr int NCAM = 6;
constexpr int H    = 64;
constexpr int W    = 224;
constexpr int NW   = NCAM * W;          // 1344
constexpr int NPF  = 256;
constexpr long long POS_ELEMS = (long long)B * NPF * H * NW; // 176,160,768
}

__device__ __forceinline__ void inv3(const float m[9], float o[9]) {
  float a = m[0], b = m[1], c = m[2];
  float d = m[3], e = m[4], f = m[5];
  float g = m[6], h = m[7], i = m[8];
  float A  =  e * i - f * h;
  float Bm = -(d * i - f * g);
  float C  =  d * h - e * g;
  float det = a * A + b * Bm + c * C;
  float r = 1.0f / det;
  o[0] = A * r;  o[1] = -(b * i - c * h) * r; o[2] =  (b * f - c * e) * r;
  o[3] = Bm * r; o[4] =  (a * i - c * g) * r; o[5] = -(a * f - c * d) * r;
  o[6] = C * r;  o[7] = -(a * h - b * g) * r; o[8] =  (a * e - b * d) * r;
}

__device__ __forceinline__ void mm3(const float* a, const float* bm, float* o) {
#pragma unroll
  for (int i = 0; i < 3; ++i) {
#pragma unroll
    for (int j = 0; j < 3; ++j) {
      o[i * 3 + j] = fmaf(a[i * 3 + 0], bm[0 * 3 + j],
                     fmaf(a[i * 3 + 1], bm[1 * 3 + j],
                          a[i * 3 + 2] * bm[2 * 3 + j]));
    }
  }
}

__global__ __launch_bounds__(256) void ipm_pos_kernel(
    const float* __restrict__ ext, const float* __restrict__ intr,
    const float* __restrict__ ida, const int* __restrict__ do_flip,
    float* __restrict__ out, int write_valid) {
  const int tid = blockIdx.x * blockDim.x + threadIdx.x;
  const int wp = tid % NW;
  const int bh = tid / NW;
  const int h  = bh % H;
  const int b  = bh / H;
  if (b >= B) return;
  const int cam = wp / W;

  const int mi = b * NCAM + cam;
  const float* E  = ext  + mi * 16;
  const float* Km = intr + mi * 9;
  const float* Am = ida  + mi * 9;

  float R[9] = {E[0], E[1], E[2], E[4], E[5], E[6], E[8], E[9], E[10]};
  const float tz = E[11];                     // extrinsic[2][3]
  float K[9], A[9];
#pragma unroll
  for (int i = 0; i < 9; ++i) { K[i] = Km[i]; A[i] = Am[i]; }

  float Ki[9], Ai[9], M[9], RM[9];
  inv3(K, Ki);
  inv3(A, Ai);
  mm3(Ki, Ai, M);   // K^-1 @ ida^-1
  mm3(R, M, RM);    // R @ (K^-1 @ ida^-1)

  const int w = wp - cam * W;
  const float xp = (float)w * (895.0f / 223.0f);  // linspace(0, W_IN-1, W)
  const float yp = (float)h * (511.0f / 63.0f);   // linspace(0, H_IN-1, H)

  float wx = fmaf(RM[0], xp, fmaf(RM[1], yp, RM[2]));
  float wy = fmaf(RM[3], xp, fmaf(RM[4], yp, RM[5]));
  float wz = fmaf(RM[6], xp, fmaf(RM[7], yp, RM[8]));

  float norm = sqrtf(wx * wx + wy * wy + wz * wz);
  norm = fmaxf(norm, 1e-12f);
  const float nz = wz / norm;
  const float depth = -tz / nz;
  const bool valid = depth > 0.0f;
  float X = (wx / norm) * depth;
  float Y = (wy / norm) * depth;
  if (*do_flip) Y = -Y;

  const float c1 = 0.2076205059304498f;     // log2(10000)/64
  const size_t cs  = (size_t)H * NW;        // channel stride = 86016
  const size_t o00 = ((size_t)b * NPF * H + h) * NW + wp;

#pragma unroll 4
  for (int k = 0; k < 64; ++k) {
    const float t  = exp2f((float)k * c1);  // 10000^(k/64) == dim_t[2k] == dim_t[2k+1]
    const float ay = Y / t;
    const float ax = X / t;
    float sy, cy, sx, cx;
    sincosf(ay, &sy, &cy);
    sincosf(ax, &sx, &cx);
    const size_t o = o00 + (size_t)(2 * k) * cs;
    out[o]            = valid ? sy : 0.0f;   // py channel 2k
    out[o + cs]       = valid ? cy : 0.0f;   // py channel 2k+1
    out[o + 128 * cs] = valid ? sx : 0.0f;   // px channel 128+2k
    out[o + 129 * cs] = valid ? cx : 0.0f;   // px channel 128+2k+1
  }

  if (write_valid) {
    out[POS_ELEMS + (size_t)bh * NW + wp] = valid ? 1.0f : 0.0f;
  }
}

extern "C" void kernel_launch(void* const* d_in, const int* in_sizes, int n_in,
                              void* d_out, int out_size, void* d_ws, size_t ws_size,
                              hipStream_t stream) {
  const float* ext  = (const float*)d_in[0];
  const float* intr = (const float*)d_in[1];
  const float* ida  = (const float*)d_in[2];
  const int*   flip = (const int*)d_in[3];
  float* out = (float*)d_out;

  const int total  = B * H * NW;            // 688,128 threads
  const int block  = 256;
  const int grid   = (total + block - 1) / block;  // 2688
  const int write_valid = ((long long)out_size > POS_ELEMS) ? 1 : 0;

  ipm_pos_kernel<<<grid, block, 0, stream>>>(ext, intr, ida, flip, out, write_valid);
}

// Round 2
// 698.921 us; speedup vs baseline: 1.0087x; 1.0087x over previous
//
#include <hip/hip_runtime.h>
#include <math.h>

namespace {
constexpr int B    = 8;
constexpr int NCAM = 6;
constexpr int H    = 64;
constexpr int W    = 224;
constexpr int NW   = NCAM * W;          // 1344
constexpr int NPF  = 256;
constexpr long long POS_ELEMS = (long long)B * NPF * H * NW; // 176,160,768
}

__device__ __forceinline__ void inv3(const float m[9], float o[9]) {
  float a = m[0], b = m[1], c = m[2];
  float d = m[3], e = m[4], f = m[5];
  float g = m[6], h = m[7], i = m[8];
  float A  =  e * i - f * h;
  float Bm = -(d * i - f * g);
  float C  =  d * h - e * g;
  float det = a * A + b * Bm + c * C;
  float r = 1.0f / det;
  o[0] = A * r;  o[1] = -(b * i - c * h) * r; o[2] =  (b * f - c * e) * r;
  o[3] = Bm * r; o[4] =  (a * i - c * g) * r; o[5] = -(a * f - c * d) * r;
  o[6] = C * r;  o[7] = -(a * h - b * g) * r; o[8] =  (a * e - b * d) * r;
}

__device__ __forceinline__ void mm3(const float* a, const float* bm, float* o) {
#pragma unroll
  for (int i = 0; i < 3; ++i) {
#pragma unroll
    for (int j = 0; j < 3; ++j) {
      o[i * 3 + j] = fmaf(a[i * 3 + 0], bm[0 * 3 + j],
                     fmaf(a[i * 3 + 1], bm[1 * 3 + j],
                          a[i * 3 + 2] * bm[2 * 3 + j]));
    }
  }
}

__global__ __launch_bounds__(256) void ipm_pos_kernel(
    const float* __restrict__ ext, const float* __restrict__ intr,
    const float* __restrict__ ida, const int* __restrict__ do_flip,
    float* __restrict__ out, int write_valid) {
  const int tid = blockIdx.x * blockDim.x + threadIdx.x;
  const int wp = tid % NW;
  const int bh = tid / NW;
  const int h  = bh % H;
  const int b  = bh / H;
  if (b >= B) return;
  const int cam = wp / W;

  const int mi = b * NCAM + cam;
  const float* E  = ext  + mi * 16;
  const float* Km = intr + mi * 9;
  const float* Am = ida  + mi * 9;

  float R[9] = {E[0], E[1], E[2], E[4], E[5], E[6], E[8], E[9], E[10]};
  const float tz = E[11];                     // extrinsic[2][3]
  float K[9], A[9];
#pragma unroll
  for (int i = 0; i < 9; ++i) { K[i] = Km[i]; A[i] = Am[i]; }

  float Ki[9], Ai[9], M[9], RM[9];
  inv3(K, Ki);
  inv3(A, Ai);
  mm3(Ki, Ai, M);   // K^-1 @ ida^-1
  mm3(R, M, RM);    // R @ (K^-1 @ ida^-1)

  const int w = wp - cam * W;
  const float xp = (float)w * (895.0f / 223.0f);  // linspace(0, W_IN-1, W)
  const float yp = (float)h * (511.0f / 63.0f);   // linspace(0, H_IN-1, H)

  float wx = fmaf(RM[0], xp, fmaf(RM[1], yp, RM[2]));
  float wy = fmaf(RM[3], xp, fmaf(RM[4], yp, RM[5]));
  float wz = fmaf(RM[6], xp, fmaf(RM[7], yp, RM[8]));

  float norm = sqrtf(wx * wx + wy * wy + wz * wz);
  norm = fmaxf(norm, 1e-12f);
  const float nz = wz / norm;
  const float depth = -tz / nz;
  const bool valid = depth > 0.0f;
  float X = (wx / norm) * depth;
  float Y = (wy / norm) * depth;
  if (*do_flip) Y = -Y;

  // Invalid pixels are masked to 0 anyway — zero their coordinates so they
  // never hit garbage/huge trig arguments (bit-exact: outputs unchanged).
  if (!valid) { X = 0.0f; Y = 0.0f; }

  const float amax = fmaxf(fabsf(X), fabsf(Y));

  const float c1     = 0.2076205059304498f;     // log2(10000)/64
  const float INV2PI = 0.15915494309189535f;    // 1/(2*pi)
  const size_t cs  = (size_t)H * NW;            // channel stride = 86016
  const size_t o00 = ((size_t)b * NPF * H + h) * NW + wp;

#pragma unroll 4
  for (int k = 0; k < 64; ++k) {
    const float inv_t = exp2f((float)(-k) * c1); // 1/t_k
    float sy, cy, sx, cx;
    if (__builtin_expect(!__any(amax * inv_t > 1000.0f), 1)) {
      // Fast path: |arg| <= 1e3 for every lane in the wave.
      // sin(a) = v_sin(fract(a/2pi)) (revolutions); error <= ~2e-4.
      const float ck = inv_t * INV2PI;
      const float ry = __builtin_amdgcn_fractf(Y * ck);
      const float rx = __builtin_amdgcn_fractf(X * ck);
      sy = __builtin_amdgcn_sinf(ry);
      cy = __builtin_amdgcn_cosf(ry);
      sx = __builtin_amdgcn_sinf(rx);
      cx = __builtin_amdgcn_cosf(rx);
    } else {
      // Exact path (bit-matches reference): full divide + libm sincos with
      // accurate range reduction, for near-horizon waves at small k.
      const float t  = exp2f((float)k * c1);     // 10000^(k/64)
      const float ay = Y / t;
      const float ax = X / t;
      sincosf(ay, &sy, &cy);
      sincosf(ax, &sx, &cx);
    }
    const size_t o = o00 + (size_t)(2 * k) * cs;
    out[o]            = valid ? sy : 0.0f;   // py channel 2k
    out[o + cs]       = valid ? cy : 0.0f;   // py channel 2k+1
    out[o + 128 * cs] = valid ? sx : 0.0f;   // px channel 128+2k
    out[o + 129 * cs] = valid ? cx : 0.0f;   // px channel 128+2k+1
  }

  if (write_valid) {
    out[POS_ELEMS + (size_t)bh * NW + wp] = valid ? 1.0f : 0.0f;
  }
}

extern "C" void kernel_launch(void* const* d_in, const int* in_sizes, int n_in,
                              void* d_out, int out_size, void* d_ws, size_t ws_size,
                              hipStream_t stream) {
  const float* ext  = (const float*)d_in[0];
  const float* intr = (const float*)d_in[1];
  const float* ida  = (const float*)d_in[2];
  const int*   flip = (const int*)d_in[3];
  float* out = (float*)d_out;

  const int total  = B * H * NW;            // 688,128 threads
  const int block  = 256;
  const int grid   = (total + block - 1) / block;  // 2688
  const int write_valid = ((long long)out_size > POS_ELEMS) ? 1 : 0;

  ipm_pos_kernel<<<grid, block, 0, stream>>>(ext, intr, ida, flip, out, write_valid);
}

// Round 3
// 689.725 us; speedup vs baseline: 1.0221x; 1.0133x over previous
//
#include <hip/hip_runtime.h>
#include <math.h>

namespace {
constexpr int B    = 8;
constexpr int NCAM = 6;
constexpr int H    = 64;
constexpr int W    = 224;
constexpr int NW   = NCAM * W;          // 1344
constexpr int NPF  = 256;
constexpr int WP4  = NW / 4;            // 336 float4-chunks per row
constexpr long long POS_ELEMS = (long long)B * NPF * H * NW; // 176,160,768
}

__device__ __forceinline__ void inv3(const float m[9], float o[9]) {
  float a = m[0], b = m[1], c = m[2];
  float d = m[3], e = m[4], f = m[5];
  float g = m[6], h = m[7], i = m[8];
  float A  =  e * i - f * h;
  float Bm = -(d * i - f * g);
  float C  =  d * h - e * g;
  float det = a * A + b * Bm + c * C;
  float r = 1.0f / det;
  o[0] = A * r;  o[1] = -(b * i - c * h) * r; o[2] =  (b * f - c * e) * r;
  o[3] = Bm * r; o[4] =  (a * i - c * g) * r; o[5] = -(a * f - c * d) * r;
  o[6] = C * r;  o[7] = -(a * h - b * g) * r; o[8] =  (a * e - b * d) * r;
}

__device__ __forceinline__ void mm3(const float* a, const float* bm, float* o) {
#pragma unroll
  for (int i = 0; i < 3; ++i) {
#pragma unroll
    for (int j = 0; j < 3; ++j) {
      o[i * 3 + j] = fmaf(a[i * 3 + 0], bm[0 * 3 + j],
                     fmaf(a[i * 3 + 1], bm[1 * 3 + j],
                          a[i * 3 + 2] * bm[2 * 3 + j]));
    }
  }
}

__global__ __launch_bounds__(256) void ipm_pos_kernel(
    const float* __restrict__ ext, const float* __restrict__ intr,
    const float* __restrict__ ida, const int* __restrict__ do_flip,
    float* __restrict__ out, int write_valid) {
  const int t   = blockIdx.x * blockDim.x + threadIdx.x;  // 0..172031
  const int wp4 = t % WP4;
  const int bh  = t / WP4;
  const int h   = bh % H;
  const int b   = bh / H;
  if (b >= B) return;
  const int wp0 = wp4 * 4;           // 4 consecutive pixels, same camera (224%4==0)
  const int cam = wp0 / W;

  const int mi = b * NCAM + cam;
  const float* E  = ext  + mi * 16;
  const float* Km = intr + mi * 9;
  const float* Am = ida  + mi * 9;

  float R[9] = {E[0], E[1], E[2], E[4], E[5], E[6], E[8], E[9], E[10]};
  const float tz = E[11];                     // extrinsic[2][3]
  float K[9], A[9];
#pragma unroll
  for (int i = 0; i < 9; ++i) { K[i] = Km[i]; A[i] = Am[i]; }

  float Ki[9], Ai[9], M[9], RM[9];
  inv3(K, Ki);
  inv3(A, Ai);
  mm3(Ki, Ai, M);   // K^-1 @ ida^-1
  mm3(R, M, RM);    // R @ (K^-1 @ ida^-1)

  const float yp   = (float)h * (511.0f / 63.0f);   // linspace(0, H_IN-1, H)
  const int   flip = *do_flip;

  float X[4], Y[4], vmask[4];
#pragma unroll
  for (int p = 0; p < 4; ++p) {
    const int w = wp0 + p - cam * W;
    const float xp = (float)w * (895.0f / 223.0f); // linspace(0, W_IN-1, W)
    float wx = fmaf(RM[0], xp, fmaf(RM[1], yp, RM[2]));
    float wy = fmaf(RM[3], xp, fmaf(RM[4], yp, RM[5]));
    float wz = fmaf(RM[6], xp, fmaf(RM[7], yp, RM[8]));
    float norm = sqrtf(wx * wx + wy * wy + wz * wz);
    norm = fmaxf(norm, 1e-12f);
    const float nz = wz / norm;
    const float depth = -tz / nz;
    const bool valid = depth > 0.0f;
    float Xp = (wx / norm) * depth;
    float Yp = (wy / norm) * depth;
    if (flip) Yp = -Yp;
    // Invalid pixels are masked to 0 downstream; zero their coords so they
    // never feed garbage/huge trig arguments (outputs unchanged).
    X[p] = valid ? Xp : 0.0f;
    Y[p] = valid ? Yp : 0.0f;
    vmask[p] = valid ? 1.0f : 0.0f;
  }
  const float amax = fmaxf(fmaxf(fabsf(X[0]), fabsf(X[1])),
                           fmaxf(fabsf(X[2]), fabsf(X[3])));
  const float amay = fmaxf(fmaxf(fabsf(Y[0]), fabsf(Y[1])),
                           fmaxf(fabsf(Y[2]), fabsf(Y[3])));
  const float ama  = fmaxf(amax, amay);

  const float c1     = 0.2076205059304498f;     // log2(10000)/64
  const float INV2PI = 0.15915494309189535f;    // 1/(2*pi)
  const size_t cs  = (size_t)H * NW;            // channel-plane stride = 86016
  const size_t o00 = ((size_t)b * NPF * H + h) * NW + wp0;  // float4-aligned

  for (int k = 0; k < 64; ++k) {
    const float inv_t = exp2f((float)(-k) * c1); // 1/10000^(k/64)
    float4 vsy, vcy, vsx, vcx;
    float sy[4], cy[4], sx[4], cx[4];
    // Fast path safe iff |arg| <= 800 rad for all lanes: then |rev| <= 127.3,
    // inside v_sin_f32's valid +-256 revolution domain (no fract needed).
    if (__builtin_expect(!__any(ama * inv_t > 800.0f), 1)) {
      const float ck = inv_t * INV2PI;
#pragma unroll
      for (int p = 0; p < 4; ++p) {
        const float ry = Y[p] * ck;              // revolutions
        const float rx = X[p] * ck;
        sy[p] = __builtin_amdgcn_sinf(ry);
        cy[p] = __builtin_amdgcn_cosf(ry);
        sx[p] = __builtin_amdgcn_sinf(rx);
        cx[p] = __builtin_amdgcn_cosf(rx);
      }
    } else {
      // Exact path (matches reference libm): divide + sincosf with full
      // range reduction, for near-horizon waves with huge arguments.
      const float tk = exp2f((float)k * c1);     // 10000^(k/64)
#pragma unroll
      for (int p = 0; p < 4; ++p) {
        sincosf(Y[p] / tk, &sy[p], &cy[p]);
        sincosf(X[p] / tk, &sx[p], &cx[p]);
      }
    }
    vsy = make_float4(sy[0] * vmask[0], sy[1] * vmask[1], sy[2] * vmask[2], sy[3] * vmask[3]);
    vcy = make_float4(cy[0] * vmask[0], cy[1] * vmask[1], cy[2] * vmask[2], cy[3] * vmask[3]);
    vsx = make_float4(sx[0] * vmask[0], sx[1] * vmask[1], sx[2] * vmask[2], sx[3] * vmask[3]);
    vcx = make_float4(cx[0] * vmask[0], cx[1] * vmask[1], cx[2] * vmask[2], cx[3] * vmask[3]);

    const size_t o = o00 + (size_t)(2 * k) * cs;
    *(float4*)(out + o)            = vsy;   // py channel 2k
    *(float4*)(out + o + cs)       = vcy;   // py channel 2k+1
    *(float4*)(out + o + 128 * cs) = vsx;   // px channel 128+2k
    *(float4*)(out + o + 129 * cs) = vcx;   // px channel 128+2k+1
  }

  if (write_valid) {
    *(float4*)(out + POS_ELEMS + (size_t)bh * NW + wp0) =
        make_float4(vmask[0], vmask[1], vmask[2], vmask[3]);
  }
}

extern "C" void kernel_launch(void* const* d_in, const int* in_sizes, int n_in,
                              void* d_out, int out_size, void* d_ws, size_t ws_size,
                              hipStream_t stream) {
  const float* ext  = (const float*)d_in[0];
  const float* intr = (const float*)d_in[1];
  const float* ida  = (const float*)d_in[2];
  const int*   flip = (const int*)d_in[3];
  float* out = (float*)d_out;

  const int total = B * H * WP4 * 4 / 4;    // 172,032 threads (4 px each)
  const int block = 256;
  const int grid  = (total + block - 1) / block;  // 672
  const int write_valid = ((long long)out_size > POS_ELEMS) ? 1 : 0;

  ipm_pos_kernel<<<grid, block, 0, stream>>>(ext, intr, ida, flip, out, write_valid);
}